// Round 1
// baseline (167.680 us; speedup 1.0000x reference)
//
#include <hip/hip_runtime.h>
#include <hip/hip_bf16.h>
#include <stdint.h>

// Problem constants (N,C,H,W = 4,128,64,64)
#define NB 4
#define CH 128
#define LL 4096   // H*W

typedef __attribute__((ext_vector_type(8))) short short8;   // 8 bf16 MFMA A/B frag
typedef __attribute__((ext_vector_type(4))) short short4b;  // 4 bf16 (8B)
typedef __attribute__((ext_vector_type(4))) float floatx4;  // 16x16 C/D frag
typedef __attribute__((ext_vector_type(16))) float floatx16; // 32x32 C/D frag

// Frag-major layout (verified R9-R13): element (row r, k) of 16-wide tile t:
//   t*2048 + (k>>5)*512 + ((k>>3)&3)*128 + (r&15)*8 + (k&7)
// One 16x16x32 frag (tile t, slice s) = 512 contiguous shorts; lane L reads
// [8L, 8L+8) — fully coalesced; identical mapping for A- and B-frags.

static __device__ __forceinline__ short f2bf(float f) {
    uint32_t u = __float_as_uint(f);
    u += 0x7fffu + ((u >> 16) & 1u);
    return (short)(u >> 16);
}
static __device__ __forceinline__ float bf2f(short s) {
    return __uint_as_float(((uint32_t)(uint16_t)s) << 16);
}

// ---------------------------------------------------------------------------
// Kernel 0: W prep — Wq/Wk/Wv fp32 [o][c] -> bf16 frag-major A-layout
// (rows=o, k=c). K-scale folded into Wk. (unchanged)
// ---------------------------------------------------------------------------
__global__ __launch_bounds__(256) void wprep_kernel(
    const float* __restrict__ Wq, const float* __restrict__ Wk,
    const float* __restrict__ Wv, short* __restrict__ Wf)
{
    const int g = blockIdx.x * 256 + threadIdx.x;   // 0..49151
    const int mat = g >> 14;
    const int rem = g & 16383;
    const int o   = rem >> 7;
    const int c   = rem & 127;
    const float* W = (mat == 0) ? Wq : (mat == 1) ? Wk : Wv;
    float v = W[o * CH + c];
    if (mat == 1) v *= 0.08838834764831845f;
    Wf[(size_t)mat * 16384 + (o >> 4) * 2048 + (c >> 5) * 512
       + ((c >> 3) & 3) * 128 + (o & 15) * 8 + (c & 7)] = f2bf(v);
}

// ---------------------------------------------------------------------------
// Kernel 1: QKV projection via MFMA (unchanged R12-proven structure).
// Outputs Qf/Kf frag-major, Vp panel [n][l>>4][c][l&15].
// grid = 4n*128 lt = 512 blocks x 256 thr.
// ---------------------------------------------------------------------------
__global__ __launch_bounds__(256) void proj_kernel(
    const float* __restrict__ x, const short* __restrict__ Wf,
    const float* __restrict__ bq, const float* __restrict__ bk,
    const float* __restrict__ bv,
    short* __restrict__ Qf, short* __restrict__ Kf, short* __restrict__ Vp)
{
    const int b    = blockIdx.x;
    const int n    = b >> 7;
    const int lt   = b & 127;         // l-tile of 32
    const int l0   = lt << 5;
    const int tid  = threadIdx.x;
    const int wave = tid >> 6;        // 0..3
    const int lane = tid & 63;
    const int quad = lane >> 4;
    const int mc   = lane & 15;

    __shared__ short Xb[32][136];     // [l][c] bf16, +8 pad (8.7 KB)

    {
        const int sl = tid & 31;      // l
        const int cg = tid >> 5;      // c-group of 16 (0..7)
        const float* xp = x + ((size_t)n * CH + cg * 16) * LL + l0 + sl;
        short8 buf;
        #pragma unroll
        for (int i = 0; i < 16; ++i) {
            buf[i & 7] = f2bf(xp[(size_t)i * LL]);
            if ((i & 7) == 7)
                *(short8*)(void*)&Xb[sl][cg * 16 + (i & 8)] = buf;
        }
    }
    __syncthreads();

    const int lt2 = wave >> 1;        // l-subtile of 16
    const int oh  = wave & 1;         // o-half (4 o-tiles)
    const int gt  = lt * 2 + lt2;     // global 16-l tile index

    short8 xf[4];                     // B-frags: B[k=c][col=l]
    #pragma unroll
    for (int s = 0; s < 4; ++s)
        xf[s] = *(const short8*)(const void*)&Xb[lt2 * 16 + mc][32 * s + quad * 8];

    const size_t obase = ((size_t)n * 256 + gt) * 2048;
    const float scale = 0.08838834764831845f;  // 1/sqrt(128)

    #pragma unroll
    for (int mat = 0; mat < 3; ++mat) {
        const short* Wm = Wf + (size_t)mat * 16384;
        const float* bb = (mat == 0) ? bq : (mat == 1) ? bk : bv;
        const float bscale = (mat == 1) ? scale : 1.0f;
        #pragma unroll
        for (int ot = oh * 4; ot < oh * 4 + 4; ++ot) {
            floatx4 acc = {0.f, 0.f, 0.f, 0.f};
            #pragma unroll
            for (int s = 0; s < 4; ++s)
                acc = __builtin_amdgcn_mfma_f32_16x16x32_bf16(
                    *(const short8*)(const void*)(Wm + ot * 2048 + s * 512 + lane * 8),
                    xf[s], acc, 0, 0, 0);
            const int c0 = ot * 16 + 4 * quad;
            if (mat < 2) {
                short4b pv;
                #pragma unroll
                for (int r = 0; r < 4; ++r)
                    pv[r] = f2bf(acc[r] + bb[c0 + r] * bscale);
                short* dst = ((mat == 0) ? Qf : Kf) + obase
                           + (c0 >> 5) * 512 + ((c0 >> 3) & 3) * 128
                           + mc * 8 + (c0 & 7);
                *(short4b*)(void*)dst = pv;
            } else {
                #pragma unroll
                for (int r = 0; r < 4; ++r)
                    Vp[obase + (c0 + r) * 16 + mc] = f2bf(acc[r] + bb[c0 + r]);
            }
        }
    }
}

// ---------------------------------------------------------------------------
// Kernel 2 (R14 rewrite): softmax denominators ONLY -> rcpD[n][l] floats.
//  - 256 blocks x 1024 thr (16 waves/CU = 4/SIMD, was 2/SIMD): 2x TLP.
//  - 4 K-tiles resident per block (halves Qf L2 re-reads vs 32-l blocks).
//  - Ping-pong Q-tile prefetch: a tile's 4 loads are in flight across the
//    previous tile's 8-MFMA substep (~620 SIMD cyc >> L2 latency).
//  - V rescale pass REMOVED (1/D now folded into attn_out phase A): kills
//    8 MB Vp->Vs round-trip + scattered 2B store tail.
// Wave w: m-eighth (w&7) x K-tile-half (w>>3). ~105 VGPR, fits 128 cap.
// ---------------------------------------------------------------------------
__global__ __launch_bounds__(1024) void rowsum_kernel(
    const short* __restrict__ Qf, const short* __restrict__ Kf,
    float* __restrict__ Dv)
{
    const int b    = blockIdx.x;         // 256 blocks
    const int n    = b >> 6;
    const int tq   = b & 63;             // 64-l group (4 K-tiles)
    const int tid  = threadIdx.x;
    const int wave = tid >> 6;           // 0..15
    const int lane = tid & 63;
    const int quad = lane >> 4;
    const int mc   = lane & 15;
    const int mw   = wave & 7;           // m-eighth (512 m = 32 q-tiles)
    const int th   = wave >> 3;          // K-tile half (2 of the 4 tiles)

    __shared__ float Db[16][32];         // per-wave partial D (2 KB)

    const short* Kb = Kf + ((size_t)n * 256 + tq * 4 + th * 2) * 2048 + lane * 8;
    short8 kf[2][4];
    #pragma unroll
    for (int t = 0; t < 2; ++t)
        #pragma unroll
        for (int s = 0; s < 4; ++s)
            kf[t][s] = *(const short8*)(const void*)(Kb + t * 2048 + s * 512);

    const short* Qn = Qf + (size_t)n * 524288 + (size_t)mw * 32 * 2048 + lane * 8;
    float rs[2][4] = {{0.f, 0.f, 0.f, 0.f}, {0.f, 0.f, 0.f, 0.f}};

    short8 qA[4], qB[4];
    #pragma unroll
    for (int s = 0; s < 4; ++s)
        qA[s] = *(const short8*)(const void*)(Qn + s * 512);

    auto qstep = [&](const short8 (&q)[4]) {
        floatx4 a0 = {0.f, 0.f, 0.f, 0.f};
        floatx4 a1 = {0.f, 0.f, 0.f, 0.f};
        #pragma unroll
        for (int s = 0; s < 4; ++s) {
            a0 = __builtin_amdgcn_mfma_f32_16x16x32_bf16(kf[0][s], q[s], a0, 0, 0, 0);
            a1 = __builtin_amdgcn_mfma_f32_16x16x32_bf16(kf[1][s], q[s], a1, 0, 0, 0);
        }
        #pragma unroll
        for (int r = 0; r < 4; ++r) {
            rs[0][r] += __expf(a0[r]);
            rs[1][r] += __expf(a1[r]);
        }
    };

    for (int it = 0; it < 32; it += 2) {
        // prefetch tile it+1 while computing tile it
        #pragma unroll
        for (int s = 0; s < 4; ++s)
            qB[s] = *(const short8*)(const void*)(
                Qn + (size_t)((it + 1) & 31) * 2048 + s * 512);
        qstep(qA);
        // prefetch tile it+2 while computing tile it+1 (wrap at end: harmless)
        #pragma unroll
        for (int s = 0; s < 4; ++s)
            qA[s] = *(const short8*)(const void*)(
                Qn + (size_t)((it + 2) & 31) * 2048 + s * 512);
        qstep(qB);
    }

    // reduce over m within wave (cols live in mc lanes), then across 8 m-waves
    #pragma unroll
    for (int t = 0; t < 2; ++t)
        #pragma unroll
        for (int r = 0; r < 4; ++r) {
            float v = rs[t][r];
            v += __shfl_xor(v, 1);
            v += __shfl_xor(v, 2);
            v += __shfl_xor(v, 4);
            v += __shfl_xor(v, 8);
            if (mc == 0) Db[wave][t * 16 + quad * 4 + r] = v;  // local l = th*32+t*16+quad*4+r
        }
    __syncthreads();
    if (tid < 64) {
        const int lh = tid >> 5, lr = tid & 31;
        float s = 0.f;
        #pragma unroll
        for (int m = 0; m < 8; ++m) s += Db[lh * 8 + m][lr];
        Dv[(size_t)n * 4096 + tq * 64 + tid] = 1.0f / s;
    }
}

// ---------------------------------------------------------------------------
// Kernel 3: O[c,m] = sum_l V[c,l]*exp(S[l,m])/D[l];  out = x + O.
// R14: 1/D folded into phase A (P = exp(S)*rcpD[l], one broadcast float4
// per step per lane); reads Vp directly (Vs buffer gone). Otherwise the
// R13 structure: m-block 64, 1024 thr, Q resident, P dbuf, 1 barrier/step.
// grid = 4n * 64 m-blocks = 256 blocks x 1024 thr.
// ---------------------------------------------------------------------------
__global__ __launch_bounds__(1024) void attn_out_kernel(
    const short* __restrict__ Qf, const short* __restrict__ Kf,
    const short* __restrict__ Vp, const float* __restrict__ Dv,
    const float* __restrict__ x, float* __restrict__ out)
{
    const int b    = blockIdx.x;
    const int n    = b >> 6;
    const int m0   = (b & 63) << 6;     // m-block of 64
    const int tid  = threadIdx.x;
    const int wave = tid >> 6;          // 0..15
    const int lane = tid & 63;
    const int quad = lane >> 4;
    const int mc   = lane & 15;
    const int l32  = lane & 31;
    const int h    = lane >> 5;
    const int ct   = wave & 3;          // c-tile (32 channels)
    const int mh   = (wave >> 2) & 1;   // m-half (32 cols)
    const int kh   = wave >> 3;         // kc-half

    __shared__ short P[2][64][264];     // dbuf [m][l-local 256 +8] (67.6 KB)
    __shared__ float Rbuf[4][2][64][16]; // kh-pair reduce (32 KB)

    const short* Qn  = Qf + (size_t)n * 524288;
    const short* Kn  = Kf + (size_t)n * 524288;
    const short* Vpn = Vp + (size_t)n * 524288;
    const float* Dn  = Dv + (size_t)n * 4096;

    // resident Q B-frags (4 m-tiles x 4 slices = 64 VGPR)
    short8 qf[4][4];
    #pragma unroll
    for (int mst = 0; mst < 4; ++mst)
        #pragma unroll
        for (int s = 0; s < 4; ++s)
            qf[mst][s] = *(const short8*)(const void*)(
                Qn + (size_t)((m0 >> 4) + mst) * 2048 + s * 512 + lane * 8);

    floatx16 acc;
    #pragma unroll
    for (int r = 0; r < 16; ++r) acc[r] = 0.f;

    for (int step = 0; step < 16; ++step) {
        const int lb = step << 8;       // 256 l per step
        const int p  = step & 1;

        // ---- phase A: wave w -> S rows [lb+16w..+16) x 64 m -> P[p] ----
        short8 kfr[4];
        #pragma unroll
        for (int s = 0; s < 4; ++s)
            kfr[s] = *(const short8*)(const void*)(
                Kn + (size_t)(step * 16 + wave) * 2048 + s * 512 + lane * 8);
        // rcpD for this lane's 4 rows (l = lb + 16*wave + 4*quad + r);
        // broadcast within 16-lane groups, issued alongside the K loads.
        const floatx4 dr = *(const floatx4*)(const void*)(
            Dn + lb + wave * 16 + quad * 4);

        #pragma unroll
        for (int mst = 0; mst < 4; ++mst) {
            floatx4 sa = {0.f, 0.f, 0.f, 0.f};
            #pragma unroll
            for (int s = 0; s < 4; ++s)
                sa = __builtin_amdgcn_mfma_f32_16x16x32_bf16(kfr[s], qf[mst][s], sa, 0, 0, 0);
            short4b pv;
            #pragma unroll
            for (int r = 0; r < 4; ++r) pv[r] = f2bf(__expf(sa[r]) * dr[r]);
            // C-layout (row=l=4q+r, col=m=mc) -> P[m][l-local]
            *(short4b*)(void*)&P[p][16 * mst + mc][16 * wave + quad * 4] = pv;
        }
        __syncthreads();   // only barrier: P[p] visible

        // ---- phase B: V panel x P[p]; wave covers kc-half (8 chunks) ----
        #pragma unroll
        for (int i = 0; i < 8; ++i) {
            const int kc = kh * 8 + i;  // 16-l chunk within the 256-l step
            const short8 vf = *(const short8*)(const void*)(
                Vpn + (size_t)((lb >> 4) + kc) * 2048 + (32 * ct + l32) * 16 + 8 * h);
            const short8 pf = *(const short8*)(const void*)&P[p][32 * mh + l32][16 * kc + 8 * h];
            acc = __builtin_amdgcn_mfma_f32_32x32x16_bf16(vf, pf, acc, 0, 0, 0);
        }
        // no trailing barrier: next step writes P[p^1]
    }

    // ---- kh-pair reduce + epilogue (32x32 C-layout) ----
    __syncthreads();
    if (kh == 1)
        *(floatx16*)(void*)&Rbuf[ct][mh][lane][0] = acc;
    __syncthreads();
    if (kh == 0) {
        const floatx16 o = *(const floatx16*)(const void*)&Rbuf[ct][mh][lane][0];
        #pragma unroll
        for (int r = 0; r < 16; ++r) {
            const int c = 32 * ct + (r & 3) + 8 * (r >> 2) + 4 * h;
            const int m = m0 + 32 * mh + l32;
            const size_t idx = ((size_t)n * CH + c) * LL + m;
            out[idx] = x[idx] + acc[r] + o[r];
        }
    }
}

// ---------------------------------------------------------------------------
extern "C" void kernel_launch(void* const* d_in, const int* in_sizes, int n_in,
                              void* d_out, int out_size, void* d_ws, size_t ws_size,
                              hipStream_t stream) {
    (void)in_sizes; (void)n_in; (void)out_size; (void)ws_size;
    const float* x  = (const float*)d_in[0];
    const float* Wq = (const float*)d_in[1];
    const float* bq = (const float*)d_in[2];
    const float* Wk = (const float*)d_in[3];
    const float* bk = (const float*)d_in[4];
    const float* Wv = (const float*)d_in[5];
    const float* bv = (const float*)d_in[6];
    float* out = (float*)d_out;

    char* ws = (char*)d_ws;
    // ws: Qf 4MB | Kf 4MB | Vp 4MB | Dv 64KB (in old Vs slot) | Wf 96KB
    short* Qf = (short*)(ws);
    short* Kf = (short*)(ws + 4194304);
    short* Vp = (short*)(ws + 8388608);
    float* Dv = (float*)(ws + 12582912);
    short* Wf = (short*)(ws + 16777216);

    wprep_kernel<<<192, 256, 0, stream>>>(Wq, Wk, Wv, Wf);
    proj_kernel<<<512, 256, 0, stream>>>(x, Wf, bq, bk, bv, Qf, Kf, Vp);
    rowsum_kernel<<<256, 1024, 0, stream>>>(Qf, Kf, Dv);
    attn_out_kernel<<<256, 1024, 0, stream>>>(Qf, Kf, Vp, Dv, x, out);
}